// Round 1
// baseline (12317.307 us; speedup 1.0000x reference)
//
#include <hip/hip_runtime.h>
#include <hip/hip_cooperative_groups.h>
#include <math.h>

namespace cg = cooperative_groups;

#define NB 128      // batch
#define NT 64       // timesteps
#define NI 512      // input dim
#define NH 1024     // hidden dim
#define NO 512      // output dim
#define PONDOFF (NB*NT*NO)

// dynamic LDS: [1024][32] w_hh column-slice, XOR-swizzled, 128 KB
extern __shared__ float smem[];

typedef unsigned long long u64;

// ---- fine-grained agent-coherent accesses (sc0 sc1: bypass L1+L2) ----
// All cross-block data (hbuf/habuf/out) moves through the L3 coherence point
// directly. NO agent acquire fence is issued in the main loop, so each XCD's
// L2 keeps wihT / x / w_out warm across intervals (previously the per-interval
// buffer_inv forced ~77 KB/block-interval of L3 refetch = FETCH_SIZE 3.5 GB).
__device__ __forceinline__ float2 ldcg2(const float* p) {
    union { u64 u; float2 f; } c;
    c.u = __hip_atomic_load((const u64*)p, __ATOMIC_RELAXED, __HIP_MEMORY_SCOPE_AGENT);
    return c.f;
}
__device__ __forceinline__ void stcg2(float* p, float a, float b) {
    union { u64 u; float2 f; } c;
    c.f = make_float2(a, b);
    __hip_atomic_store((u64*)p, c.u, __ATOMIC_RELAXED, __HIP_MEMORY_SCOPE_AGENT);
}
__device__ __forceinline__ void stcg1(float* p, float v) {
    union { unsigned u; float f; } c; c.f = v;
    __hip_atomic_store((unsigned*)p, c.u, __ATOMIC_RELAXED, __HIP_MEMORY_SCOPE_AGENT);
}

// Per-group (32-block) barrier, v4:
//  - arrival: RELEASE fetch_add (prior sc1 write-through stores are ordered
//    ahead of the increment at the coherence point; L2 is ~clean so the
//    release writeback is cheap)
//  - poll: ONE lane, agent-scope atomic LOAD (sc0 sc1 -> always fresh at L3;
//    unlike the old fetch_add(0) poll it takes no exclusive ownership, so 32
//    pollers no longer serialize a hot-line RMW queue)
//  - NO acquire fence: cross-block data is read exclusively via sc0 sc1
//    loads, which cannot hit a stale cache. The trailing __syncthreads is a
//    compiler memory barrier and orders the other waves behind the poll.
__device__ __forceinline__ void group_barrier(unsigned* ctr, unsigned target, int tid)
{
    __syncthreads();
    if (tid == 0) {
        __hip_atomic_fetch_add(ctr, 1u, __ATOMIC_RELEASE, __HIP_MEMORY_SCOPE_AGENT);
        while (__hip_atomic_load(ctr, __ATOMIC_RELAXED, __HIP_MEMORY_SCOPE_AGENT) < target)
            __builtin_amdgcn_s_sleep(2);
    }
    __syncthreads();
}

// 256 blocks x 1024 threads. 8 groups x 32 blocks; group owns 16 batch rows,
// block owns a 32-col slice. ASYNC ROW SCHEDULING: every interval, every
// unfinished row executes one step (main or ponder) at its OWN timestep.
// All 32 blocks replicate the (deterministic, bit-identical) decision state
// machine -> uniform control flow.
__global__ void __launch_bounds__(1024, 1)
arnn_coop(const float* __restrict__ x, const float* __restrict__ s0,
          const float* __restrict__ w_ih, const float* __restrict__ w_hh,
          const float* __restrict__ b_ih, const float* __restrict__ b_hh,
          const float* __restrict__ w_halt, const float* __restrict__ b_halt,
          const float* __restrict__ w_out, const float* __restrict__ b_out,
          float* __restrict__ out, float* __restrict__ ws)
{
    cg::grid_group grid = cg::this_grid();
    const int tid = threadIdx.x;
    const int bid = blockIdx.x;
    const int gid = bid * 1024 + tid;

    // ws layout (floats)
    float* wihT  = ws;                       // [NI][NH]
    float* hbuf  = wihT + NI*NH;             // [NB][2][NH] per-row ping-pong h
    float* habuf = hbuf + NB*2*NH;           // [2][NB][NH] timestep-parity h_acc
    unsigned* ctrA = (unsigned*)(habuf + 2*NB*NH);  // [8][32] arrival ctrs, 128B stride

    const int gp = bid >> 5, lb = bid & 31;

    // s_whalt padded +4 floats per 16: b128 read at lane*20+q touches all 32
    // banks uniformly (8/bank = minimum) instead of the 32-way conflict of
    // the unpadded lane*16+q layout (was ~10% of CU-cycles in BANK_CONFLICT).
    __shared__ float s_whalt[NH + (NH/16)*4];        // 5 KB
    __shared__ int   s_t[16];
    __shared__ float s_cum[16];
    __shared__ int   s_n[16];
    __shared__ int   s_et[16], s_en[16];
    __shared__ unsigned char s_sl[16];
    __shared__ unsigned char s_run[16];
    __shared__ unsigned char s_mode[16];
    __shared__ unsigned char s_epi[16];

    // ---- phase 0 ----
    for (int e = gid; e < NI*NH; e += 256*1024) {
        const int i = e >> 10, jj = e & 1023;
        wihT[e] = w_ih[jj*(NI+1) + 1 + i];
    }
    if (gid < 8*32)
        __hip_atomic_store(&ctrA[gid], 0u, __ATOMIC_RELAXED, __HIP_MEMORY_SCOPE_AGENT);
    // stage this block's w_hh column slice into LDS, XOR-swizzled:
    // element (k, j) at float offset k*32 + ((j>>1)^((k>>6)&15))*2 + (j&1)
    for (int e = tid; e < 1024*32; e += 1024) {
        const int k = e & 1023, jj = e >> 10;
        const float v = w_hh[(lb*32 + jj)*NH + k];
        const int su = (jj >> 1) ^ ((k >> 6) & 15);
        smem[k*32 + su*2 + (jj & 1)] = v;
    }
    {
        const int j = tid;
        s_whalt[j + ((j >> 4) << 2)] = w_halt[j];
    }
    if (tid < 16) {
        s_t[tid] = 0; s_cum[tid] = 0.0f; s_n[tid] = 0;
        s_et[tid] = 0; s_en[tid] = 0;
        s_sl[tid] = 0; s_run[tid] = 1; s_mode[tid] = 0; s_epi[tid] = 0;
    }
    grid.sync();

    unsigned* ctr = ctrA + gp*32;

    const int w    = tid >> 6;
    const int lane = tid & 63;
    const int rq   = w >> 2;                 // row quad 0..3
    const int co   = w & 3;                  // col octet 0..3
    const int up   = lane & 3;               // col pair in octet
    const int ks   = lane >> 2;              // k-slice 0..15 (64 wide)
    const int u    = co*4 + up;              // col pair in block 0..15
    const int jg   = lb*32 + u*2;            // global col (pair base)
    const int b0   = gp*16 + rq*4;           // first of my 4 matmul rows
    const bool k0  = (ks == 0);
    const int ldsb = ks*2048 + ((u ^ ks) << 1);

    const float bh  = b_halt[0];
    const float bias0 = k0 ? (b_ih[jg]   + b_hh[jg])   : 0.0f;
    const float bias1 = k0 ? (b_ih[jg+1] + b_hh[jg+1]) : 0.0f;
    const float w0a   = k0 ? w_ih[jg*(NI+1)]     : 0.0f;
    const float w0b   = k0 ? w_ih[(jg+1)*(NI+1)] : 0.0f;

    // epilogue mapping: wave = row, lane = (ocol 0..15, kquarter 0..3)
    const int   eo = lb*16 + (lane & 15);
    const int   eq = lane >> 4;
    const int   eb = gp*16 + w;
    const float bo = b_out[eo];

    // decision mini-dot: wave w owns row gp*16+w; fixed tree = identical bits
    auto decide_p = [&](int slot) -> float {
        const float* hr = hbuf + ((gp*16 + w)*2 + slot)*NH + lane*16;
        float d = 0.0f;
        #pragma unroll
        for (int q = 0; q < 16; q += 4) {
            const float2 h1 = ldcg2(hr + q);
            const float2 h2 = ldcg2(hr + q + 2);
            const float4 wv = *(const float4*)(&s_whalt[lane*20 + q]);
            d += h1.x*wv.x + h1.y*wv.y + h2.x*wv.z + h2.y*wv.w;
        }
        d += __shfl_xor(d, 1);  d += __shfl_xor(d, 2);  d += __shfl_xor(d, 4);
        d += __shfl_xor(d, 8);  d += __shfl_xor(d, 16); d += __shfl_xor(d, 32);
        return 1.0f / (1.0f + expf(-(d + bh)));
    };

    float xw[4][2];                          // per-row x-part, persists over ponder
    float hacc[4][2];                        // per-(row,colpair) h_acc, k0 lanes own it

    unsigned gen = 0;
    for (;;) {
        // ================= compute phase =================
        // ---- epilogue for my decide-row, if pending ----
        if (s_epi[w]) {
            const int et = s_et[w];
            const float* hap = habuf + (et&1)*(NB*NH) + eb*NH + eq*256;
            const float* wq = w_out + eo*NH + eq*256;
            float acc = 0.0f;
            #pragma unroll 4
            for (int jj2 = 0; jj2 < 256; jj2 += 4) {
                const float2 h1 = ldcg2(hap + jj2);
                const float2 h2 = ldcg2(hap + jj2 + 2);
                const float4 wv = *(const float4*)(wq + jj2);
                acc += h1.x*wv.x + h1.y*wv.y + h2.x*wv.z + h2.y*wv.w;
            }
            acc += __shfl_xor(acc, 16); acc += __shfl_xor(acc, 32);
            if (eq == 0) stcg1(&out[(eb*NT + et)*NO + eo], acc + (float)s_en[w]*bo);
        }
        // ---- one step for each of my 4 matmul rows ----
        int ex[4], md[4], tt[4], sl[4];
        #pragma unroll
        for (int r = 0; r < 4; ++r) {
            const int rr = rq*4 + r;
            ex[r] = s_run[rr]; md[r] = s_mode[rr]; tt[r] = s_t[rr]; sl[r] = s_sl[rr];
        }
        if (ex[0] | ex[1] | ex[2] | ex[3]) {
            // x-part for rows starting a timestep (wave-uniform branches);
            // x and wihT are read-only -> normal cached loads, stay warm in L2
            #pragma unroll
            for (int r = 0; r < 4; ++r) {
                if (ex[r] && md[r] == 0) {
                    float o0 = bias0, o1 = bias1;
                    const float* xr = x + ((b0+r)*NT + tt[r])*NI + ks*32;
                    const float* wp = wihT + (ks*32)*NH + jg;
                    #pragma unroll 4
                    for (int i = 0; i < 32; i += 4) {
                        const float4 xv = *(const float4*)(xr + i);
                        const float2 wa = *(const float2*)(wp + (i  )*NH);
                        const float2 wb = *(const float2*)(wp + (i+1)*NH);
                        const float2 wc = *(const float2*)(wp + (i+2)*NH);
                        const float2 wd = *(const float2*)(wp + (i+3)*NH);
                        o0 += xv.x*wa.x + xv.y*wb.x + xv.z*wc.x + xv.w*wd.x;
                        o1 += xv.x*wa.y + xv.y*wb.y + xv.z*wc.y + xv.w*wd.y;
                    }
                    xw[r][0] = o0; xw[r][1] = o1;
                }
            }
            // hh matmul: per-row source by mode; dead rows compute garbage
            // (discarded). h is cross-block -> coherent sc1 loads.
            float a[4][2];
            const float* hp[4];
            #pragma unroll
            for (int r = 0; r < 4; ++r) {
                const int b = b0 + r;
                a[r][0] = xw[r][0] + (md[r] == 0 ? w0a : 0.0f);
                a[r][1] = xw[r][1] + (md[r] == 0 ? w0b : 0.0f);
                if (!ex[r])           hp[r] = hbuf + (b*2)*NH + ks*64;
                else if (md[r] == 0)  hp[r] = (tt[r] == 0 ? s0 + b*NH
                                              : habuf + ((tt[r]-1)&1)*(NB*NH) + b*NH) + ks*64;
                else                  hp[r] = hbuf + (b*2 + sl[r])*NH + ks*64;
            }
            #pragma unroll 4
            for (int kc = 0; kc < 64; kc += 4) {
                const float2 h0a = ldcg2(hp[0] + kc), h0b = ldcg2(hp[0] + kc + 2);
                const float2 h1a = ldcg2(hp[1] + kc), h1b = ldcg2(hp[1] + kc + 2);
                const float2 h2a = ldcg2(hp[2] + kc), h2b = ldcg2(hp[2] + kc + 2);
                const float2 h3a = ldcg2(hp[3] + kc), h3b = ldcg2(hp[3] + kc + 2);
                const float2 wa = *(const float2*)(smem + ldsb + (kc  )*32);
                const float2 wb = *(const float2*)(smem + ldsb + (kc+1)*32);
                const float2 wc = *(const float2*)(smem + ldsb + (kc+2)*32);
                const float2 wd = *(const float2*)(smem + ldsb + (kc+3)*32);
                a[0][0] += h0a.x*wa.x + h0a.y*wb.x + h0b.x*wc.x + h0b.y*wd.x;
                a[0][1] += h0a.x*wa.y + h0a.y*wb.y + h0b.x*wc.y + h0b.y*wd.y;
                a[1][0] += h1a.x*wa.x + h1a.y*wb.x + h1b.x*wc.x + h1b.y*wd.x;
                a[1][1] += h1a.x*wa.y + h1a.y*wb.y + h1b.x*wc.y + h1b.y*wd.y;
                a[2][0] += h2a.x*wa.x + h2a.y*wb.x + h2b.x*wc.x + h2b.y*wd.x;
                a[2][1] += h2a.x*wa.y + h2a.y*wb.y + h2b.x*wc.y + h2b.y*wd.y;
                a[3][0] += h3a.x*wa.x + h3a.y*wb.x + h3b.x*wc.x + h3b.y*wd.x;
                a[3][1] += h3a.x*wa.y + h3a.y*wb.y + h3b.x*wc.y + h3b.y*wd.y;
            }
            #pragma unroll
            for (int r = 0; r < 4; ++r)
                #pragma unroll
                for (int c = 0; c < 2; ++c) {
                    float v = a[r][c];
                    v += __shfl_xor(v, 4);  v += __shfl_xor(v, 8);
                    v += __shfl_xor(v, 16); v += __shfl_xor(v, 32);
                    a[r][c] = v;
                }
            if (k0) {
                #pragma unroll
                for (int r = 0; r < 4; ++r) {
                    if (ex[r]) {
                        const float ha = tanhf(a[r][0]), hb = tanhf(a[r][1]);
                        const int b = b0 + r;
                        stcg2(hbuf + (b*2 + (sl[r]^1))*NH + jg, ha, hb);
                        // h_acc accumulates in registers (this lane is the sole
                        // owner of (b, jg)); publish the running value for
                        // cross-block readers (epilogue / next-t main step).
                        if (md[r] == 0) { hacc[r][0] = ha;  hacc[r][1] = hb; }
                        else            { hacc[r][0] += ha; hacc[r][1] += hb; }
                        stcg2(habuf + (tt[r]&1)*(NB*NH) + b*NH + jg,
                              hacc[r][0], hacc[r][1]);
                    }
                }
            }
        }
        // ================= barrier =================
        ++gen; group_barrier(ctr, 32*gen, tid);
        // ================= decide + state update (row w, bit-identical) ========
        const int exw = s_run[w];
        float p = 0.0f;
        if (exw) p = decide_p(s_sl[w] ^ 1);
        if (lane == 0) {
            int newepi = 0;
            if (exw) {
                const int t = s_t[w];
                float cum; int n;
                if (s_mode[w] == 0) {
                    cum = p; n = 1;
                    if (lb == 0)
                        stcg1(&out[PONDOFF + (gp*16 + w)*NT + t],
                              (p >= 0.99f) ? 2.0f : 0.0f);
                } else {
                    cum = s_cum[w] + p; n = s_n[w] + 1;
                }
                s_cum[w] = cum; s_n[w] = n;
                s_sl[w] ^= 1;
                if ((cum < 0.99f) && n < 12) {
                    s_mode[w] = 1;
                } else {                     // timestep finished
                    newepi = 1; s_et[w] = t; s_en[w] = n;
                    if (t == NT-1) s_run[w] = 0;
                    else { s_t[w] = t + 1; s_mode[w] = 0; }
                }
            }
            s_epi[w] = newepi;
        }
        __syncthreads();
        // alive check: every wave computes it from LDS (uniform result),
        // no extra __syncthreads / broadcast needed
        const int al = (lane < 16) ? (s_run[lane] | s_epi[lane]) : 0;
        if (__ballot(al) == 0ULL) break;
    }
}

extern "C" void kernel_launch(void* const* d_in, const int* in_sizes, int n_in,
                              void* d_out, int out_size, void* d_ws, size_t ws_size,
                              hipStream_t stream) {
    const float* x      = (const float*)d_in[0];
    const float* s0     = (const float*)d_in[1];
    const float* w_ih   = (const float*)d_in[2];
    const float* w_hh   = (const float*)d_in[3];
    const float* b_ih   = (const float*)d_in[4];
    const float* b_hh   = (const float*)d_in[5];
    const float* w_halt = (const float*)d_in[6];
    const float* b_halt = (const float*)d_in[7];
    const float* w_out  = (const float*)d_in[8];
    const float* b_out  = (const float*)d_in[9];
    float* out = (float*)d_out;
    float* ws  = (float*)d_ws;

    static const int kLds = 131072;
    hipFuncSetAttribute((const void*)arnn_coop,
                        hipFuncAttributeMaxDynamicSharedMemorySize, kLds);

    void* args[] = { (void*)&x, (void*)&s0, (void*)&w_ih, (void*)&w_hh,
                     (void*)&b_ih, (void*)&b_hh, (void*)&w_halt, (void*)&b_halt,
                     (void*)&w_out, (void*)&b_out, (void*)&out, (void*)&ws };
    hipLaunchCooperativeKernel((void*)arnn_coop, dim3(256), dim3(1024), args, kLds, stream);
}

// Round 3
// 9414.693 us; speedup vs baseline: 1.3083x; 1.3083x over previous
//
#include <hip/hip_runtime.h>
#include <hip/hip_cooperative_groups.h>
#include <math.h>

namespace cg = cooperative_groups;

#define NB 128      // batch
#define NT 64       // timesteps
#define NI 512      // input dim
#define NH 1024     // hidden dim
#define NO 512      // output dim
#define PONDOFF (NB*NT*NO)

// dynamic LDS: [1024][32] w_hh column-slice, XOR-swizzled, 128 KB
extern __shared__ float smem[];

// Per-group (32-block) barrier, v6: round-0 protocol with the poll RMW
// replaced by a relaxed agent-scope atomic LOAD (proven correct in round 1).
//  - arrival: fetch_add(1, RELEASE, agent). The release lowers to
//    vmcnt-drain + L2 writeback, publishing this block's plain h-stores to
//    L3 before the increment lands (this is what makes plain-load readers
//    on other XCDs correct after their acquire).
//  - poll: ONE leader lane does a relaxed agent atomic load (sc0 sc1 ->
//    always fresh at the coherence point). Unlike the old fetch_add(0) poll
//    it takes NO exclusive ownership of the line, so 256 grid-wide pollers
//    no longer serialize an RMW queue that every arrival must join.
//  - acquire: fence by wave 0 only (cache invalidates are physically
//    CU-wide); __syncthreads orders the other waves behind it.
__device__ __forceinline__ void group_barrier(unsigned* ctr, unsigned target, int tid)
{
    __syncthreads();
    if (tid == 0) {
        __hip_atomic_fetch_add(ctr, 1u, __ATOMIC_RELEASE, __HIP_MEMORY_SCOPE_AGENT);
        while (__hip_atomic_load(ctr, __ATOMIC_RELAXED, __HIP_MEMORY_SCOPE_AGENT) < target)
            __builtin_amdgcn_s_sleep(1);
    }
    if (tid < 64)
        __builtin_amdgcn_fence(__ATOMIC_ACQUIRE, "agent");
    __syncthreads();
}

// 256 blocks x 1024 threads. 8 groups x 32 blocks; group owns 16 batch rows,
// block owns a 32-col slice. ASYNC ROW SCHEDULING: every interval, every
// unfinished row executes one step (main or ponder) at its OWN timestep;
// rows never wait for siblings. All 32 blocks replicate the (deterministic,
// bit-identical) decision state machine -> uniform control flow, barriers
// carry only h data + one arrival RMW.
__global__ void __launch_bounds__(1024, 1)
arnn_coop(const float* __restrict__ x, const float* __restrict__ s0,
          const float* __restrict__ w_ih, const float* __restrict__ w_hh,
          const float* __restrict__ b_ih, const float* __restrict__ b_hh,
          const float* __restrict__ w_halt, const float* __restrict__ b_halt,
          const float* __restrict__ w_out, const float* __restrict__ b_out,
          float* __restrict__ out, float* __restrict__ ws)
{
    cg::grid_group grid = cg::this_grid();
    const int tid = threadIdx.x;
    const int bid = blockIdx.x;
    const int gid = bid * 1024 + tid;

    // ws layout (floats)
    float* wihT  = ws;                       // [NI][NH]  wihT[i*NH+j] = w_ih[j][1+i]
    float* hbuf  = wihT + NI*NH;             // [NB][2][NH] per-row ping-pong h
    float* habuf = hbuf + NB*2*NH;           // [2][NB][NH] timestep-parity h_acc
    unsigned* ctrA = (unsigned*)(habuf + 2*NB*NH);  // [8][32] arrival ctrs, 128B stride

    const int gp = bid >> 5, lb = bid & 31;

    // s_whalt padded +4 floats per 16: the b128 read at lane*20+q spreads 64
    // lanes over all 32 banks (8/bank = wave64 minimum) instead of the
    // 32-way conflict of the unpadded lane*16+q layout.
    __shared__ float s_whalt[NH + (NH/16)*4];        // 5 KB
    // per-row replicated state (identical in all 32 blocks of the group)
    __shared__ int   s_t[16];                // current timestep
    __shared__ float s_cum[16];
    __shared__ int   s_n[16];                // steps executed this timestep
    __shared__ int   s_et[16], s_en[16];     // pending epilogue: timestep, n
    __shared__ unsigned char s_sl[16];       // hbuf slot last written
    __shared__ unsigned char s_run[16];      // row still has steps to run
    __shared__ unsigned char s_mode[16];     // 0=main, 1=ponder (next step)
    __shared__ unsigned char s_epi[16];      // epilogue pending this interval

    // ---- phase 0 ----
    for (int e = gid; e < NI*NH; e += 256*1024) {
        const int i = e >> 10, jj = e & 1023;
        wihT[e] = w_ih[jj*(NI+1) + 1 + i];
    }
    if (gid < 8*32)
        __hip_atomic_store(&ctrA[gid], 0u, __ATOMIC_RELAXED, __HIP_MEMORY_SCOPE_AGENT);
    // stage this block's w_hh column slice into LDS, XOR-swizzled:
    // element (k, j) at float offset k*32 + ((j>>1)^((k>>6)&15))*2 + (j&1)
    for (int e = tid; e < 1024*32; e += 1024) {
        const int k = e & 1023, jj = e >> 10;
        const float v = w_hh[(lb*32 + jj)*NH + k];
        const int su = (jj >> 1) ^ ((k >> 6) & 15);
        smem[k*32 + su*2 + (jj & 1)] = v;
    }
    {
        const int j = tid;
        s_whalt[j + ((j >> 4) << 2)] = w_halt[j];
    }
    if (tid < 16) {
        s_t[tid] = 0; s_cum[tid] = 0.0f; s_n[tid] = 0;
        s_et[tid] = 0; s_en[tid] = 0;
        s_sl[tid] = 0; s_run[tid] = 1; s_mode[tid] = 0; s_epi[tid] = 0;
    }
    grid.sync();

    unsigned* ctr = ctrA + gp*32;

    const int w    = tid >> 6;
    const int lane = tid & 63;
    const int rq   = w >> 2;                 // row quad 0..3
    const int co   = w & 3;                  // col octet 0..3
    const int up   = lane & 3;               // col pair in octet
    const int ks   = lane >> 2;              // k-slice 0..15 (64 wide)
    const int u    = co*4 + up;              // col pair in block 0..15
    const int jg   = lb*32 + u*2;            // global col (pair base)
    const int b0   = gp*16 + rq*4;           // first of my 4 matmul rows
    const bool k0  = (ks == 0);
    const int ldsb = ks*2048 + ((u ^ ks) << 1);

    const float bh  = b_halt[0];
    const float bias0 = k0 ? (b_ih[jg]   + b_hh[jg])   : 0.0f;
    const float bias1 = k0 ? (b_ih[jg+1] + b_hh[jg+1]) : 0.0f;
    const float w0a   = k0 ? w_ih[jg*(NI+1)]     : 0.0f;
    const float w0b   = k0 ? w_ih[(jg+1)*(NI+1)] : 0.0f;

    // epilogue mapping: wave = row, lane = (ocol 0..15, kquarter 0..3)
    const int   eo = lb*16 + (lane & 15);
    const int   eq = lane >> 4;
    const int   eb = gp*16 + w;
    const float bo = b_out[eo];

    // decision mini-dot: wave w owns row gp*16+w; fixed tree = identical bits
    auto decide_p = [&](int slot) -> float {
        const float* hr = hbuf + ((gp*16 + w)*2 + slot)*NH + lane*16;
        float d = 0.0f;
        #pragma unroll
        for (int q = 0; q < 16; q += 4) {
            const float4 hv = *(const float4*)(hr + q);
            const float4 wv = *(const float4*)(&s_whalt[lane*20 + q]);
            d += hv.x*wv.x + hv.y*wv.y + hv.z*wv.z + hv.w*wv.w;
        }
        d += __shfl_xor(d, 1);  d += __shfl_xor(d, 2);  d += __shfl_xor(d, 4);
        d += __shfl_xor(d, 8);  d += __shfl_xor(d, 16); d += __shfl_xor(d, 32);
        return 1.0f / (1.0f + expf(-(d + bh)));
    };

    float xw[4][2];                          // per-row x-part, persists over ponder
    float hacc[4][2];                        // per-(row,colpair) h_acc, k0 lanes own it

    unsigned gen = 0;
    for (;;) {
        // ================= compute phase =================
        // ---- epilogue for my decide-row, if pending ----
        if (s_epi[w]) {
            const int et = s_et[w];
            const float* ha = habuf + (et&1)*(NB*NH) + eb*NH + eq*256;
            const float* wq = w_out + eo*NH + eq*256;
            float acc = 0.0f;
            #pragma unroll 4
            for (int jj2 = 0; jj2 < 256; jj2 += 4) {
                const float4 hv = *(const float4*)(ha + jj2);
                const float4 wv = *(const float4*)(wq + jj2);
                acc += hv.x*wv.x + hv.y*wv.y + hv.z*wv.z + hv.w*wv.w;
            }
            acc += __shfl_xor(acc, 16); acc += __shfl_xor(acc, 32);
            if (eq == 0) out[(eb*NT + et)*NO + eo] = acc + (float)s_en[w]*bo;
        }
        // ---- one step for each of my 4 matmul rows ----
        int ex[4], md[4], tt[4], sl[4];
        #pragma unroll
        for (int r = 0; r < 4; ++r) {
            const int rr = rq*4 + r;
            ex[r] = s_run[rr]; md[r] = s_mode[rr]; tt[r] = s_t[rr]; sl[r] = s_sl[rr];
        }
        if (ex[0] | ex[1] | ex[2] | ex[3]) {
            // x-part for rows starting a timestep (wave-uniform branches)
            #pragma unroll
            for (int r = 0; r < 4; ++r) {
                if (ex[r] && md[r] == 0) {
                    float o0 = bias0, o1 = bias1;
                    const float* xr = x + ((b0+r)*NT + tt[r])*NI + ks*32;
                    const float* wp = wihT + (ks*32)*NH + jg;
                    #pragma unroll 4
                    for (int i = 0; i < 32; i += 4) {
                        const float4 xv = *(const float4*)(xr + i);
                        const float2 wa = *(const float2*)(wp + (i  )*NH);
                        const float2 wb = *(const float2*)(wp + (i+1)*NH);
                        const float2 wc = *(const float2*)(wp + (i+2)*NH);
                        const float2 wd = *(const float2*)(wp + (i+3)*NH);
                        o0 += xv.x*wa.x + xv.y*wb.x + xv.z*wc.x + xv.w*wd.x;
                        o1 += xv.x*wa.y + xv.y*wb.y + xv.z*wc.y + xv.w*wd.y;
                    }
                    xw[r][0] = o0; xw[r][1] = o1;
                }
            }
            // hh matmul: per-row source by mode; dead rows compute garbage (discarded)
            float a[4][2];
            const float* hp[4];
            #pragma unroll
            for (int r = 0; r < 4; ++r) {
                const int b = b0 + r;
                a[r][0] = xw[r][0] + (md[r] == 0 ? w0a : 0.0f);
                a[r][1] = xw[r][1] + (md[r] == 0 ? w0b : 0.0f);
                if (!ex[r])           hp[r] = hbuf + (b*2)*NH + ks*64;
                else if (md[r] == 0)  hp[r] = (tt[r] == 0 ? s0 + b*NH
                                              : habuf + ((tt[r]-1)&1)*(NB*NH) + b*NH) + ks*64;
                else                  hp[r] = hbuf + (b*2 + sl[r])*NH + ks*64;
            }
            #pragma unroll 4
            for (int kc = 0; kc < 64; kc += 4) {
                const float4 h0 = *(const float4*)(hp[0] + kc);
                const float4 h1 = *(const float4*)(hp[1] + kc);
                const float4 h2 = *(const float4*)(hp[2] + kc);
                const float4 h3 = *(const float4*)(hp[3] + kc);
                const float2 wa = *(const float2*)(smem + ldsb + (kc  )*32);
                const float2 wb = *(const float2*)(smem + ldsb + (kc+1)*32);
                const float2 wc = *(const float2*)(smem + ldsb + (kc+2)*32);
                const float2 wd = *(const float2*)(smem + ldsb + (kc+3)*32);
                a[0][0] += h0.x*wa.x + h0.y*wb.x + h0.z*wc.x + h0.w*wd.x;
                a[0][1] += h0.x*wa.y + h0.y*wb.y + h0.z*wc.y + h0.w*wd.y;
                a[1][0] += h1.x*wa.x + h1.y*wb.x + h1.z*wc.x + h1.w*wd.x;
                a[1][1] += h1.x*wa.y + h1.y*wb.y + h1.z*wc.y + h1.w*wd.y;
                a[2][0] += h2.x*wa.x + h2.y*wb.x + h2.z*wc.x + h2.w*wd.x;
                a[2][1] += h2.x*wa.y + h2.y*wb.y + h2.z*wc.y + h2.w*wd.y;
                a[3][0] += h3.x*wa.x + h3.y*wb.x + h3.z*wc.x + h3.w*wd.x;
                a[3][1] += h3.x*wa.y + h3.y*wb.y + h3.z*wc.y + h3.w*wd.y;
            }
            #pragma unroll
            for (int r = 0; r < 4; ++r)
                #pragma unroll
                for (int c = 0; c < 2; ++c) {
                    float v = a[r][c];
                    v += __shfl_xor(v, 4);  v += __shfl_xor(v, 8);
                    v += __shfl_xor(v, 16); v += __shfl_xor(v, 32);
                    a[r][c] = v;
                }
            if (k0) {
                #pragma unroll
                for (int r = 0; r < 4; ++r) {
                    if (ex[r]) {
                        const float ha = tanhf(a[r][0]), hb = tanhf(a[r][1]);
                        const int b = b0 + r;
                        *(float2*)(hbuf + (b*2 + (sl[r]^1))*NH + jg) = make_float2(ha, hb);
                        // h_acc accumulates in registers (this lane is the sole
                        // owner of (b, jg)); publish the running value for
                        // cross-block readers (epilogue / next-t main step).
                        if (md[r] == 0) { hacc[r][0] = ha;  hacc[r][1] = hb; }
                        else            { hacc[r][0] += ha; hacc[r][1] += hb; }
                        *(float2*)(habuf + (tt[r]&1)*(NB*NH) + b*NH + jg) =
                            make_float2(hacc[r][0], hacc[r][1]);
                    }
                }
            }
        }
        // ================= barrier =================
        ++gen; group_barrier(ctr, 32*gen, tid);
        // ================= decide + state update (row w, bit-identical) ========
        const int exw = s_run[w];
        float p = 0.0f;
        if (exw) p = decide_p(s_sl[w] ^ 1);
        if (lane == 0) {
            int newepi = 0;
            if (exw) {
                const int t = s_t[w];
                float cum; int n;
                if (s_mode[w] == 0) {
                    cum = p; n = 1;
                    if (lb == 0) out[PONDOFF + (gp*16 + w)*NT + t] = (p >= 0.99f) ? 2.0f : 0.0f;
                } else {
                    cum = s_cum[w] + p; n = s_n[w] + 1;
                }
                s_cum[w] = cum; s_n[w] = n;
                s_sl[w] ^= 1;
                if ((cum < 0.99f) && n < 12) {
                    s_mode[w] = 1;
                } else {                     // timestep finished
                    newepi = 1; s_et[w] = t; s_en[w] = n;
                    if (t == NT-1) s_run[w] = 0;
                    else { s_t[w] = t + 1; s_mode[w] = 0; }
                }
            }
            s_epi[w] = newepi;
        }
        __syncthreads();
        // alive check: every wave computes it from LDS (uniform result),
        // no extra __syncthreads / broadcast needed
        const int al = (lane < 16) ? (s_run[lane] | s_epi[lane]) : 0;
        if (__ballot(al) == 0ULL) break;
    }
}

extern "C" void kernel_launch(void* const* d_in, const int* in_sizes, int n_in,
                              void* d_out, int out_size, void* d_ws, size_t ws_size,
                              hipStream_t stream) {
    const float* x      = (const float*)d_in[0];
    const float* s0     = (const float*)d_in[1];
    const float* w_ih   = (const float*)d_in[2];
    const float* w_hh   = (const float*)d_in[3];
    const float* b_ih   = (const float*)d_in[4];
    const float* b_hh   = (const float*)d_in[5];
    const float* w_halt = (const float*)d_in[6];
    const float* b_halt = (const float*)d_in[7];
    const float* w_out  = (const float*)d_in[8];
    const float* b_out  = (const float*)d_in[9];
    float* out = (float*)d_out;
    float* ws  = (float*)d_ws;

    static const int kLds = 131072;
    hipFuncSetAttribute((const void*)arnn_coop,
                        hipFuncAttributeMaxDynamicSharedMemorySize, kLds);

    void* args[] = { (void*)&x, (void*)&s0, (void*)&w_ih, (void*)&w_hh,
                     (void*)&b_ih, (void*)&b_hh, (void*)&w_halt, (void*)&b_halt,
                     (void*)&w_out, (void*)&b_out, (void*)&out, (void*)&ws };
    hipLaunchCooperativeKernel((void*)arnn_coop, dim3(256), dim3(1024), args, kLds, stream);
}